// Round 4
// baseline (146.394 us; speedup 1.0000x reference)
//
#include <hip/hip_runtime.h>

// Problem constants (fixed by reference).
#define TT   512
#define BB   2048
#define NTAG 16
#define CH   8              // timesteps staged per chunk
#define NCH  (TT / CH)      // 64 chunks
#define BBN  (BB * NTAG)

typedef float v2f __attribute__((ext_vector_type(2)));

// ---------- DPP helpers ----------
#define DPP_XOR1  0xB1    // quad_perm [1,0,3,2] : lane ^ 1
#define DPP_XOR2  0x4E    // quad_perm [2,3,0,1] : lane ^ 2
#define DPP_XOR3  0x1B    // quad_perm [3,2,1,0] : lane ^ 3
#define DPP_ROR4  0x124   // dst lane g gets src from gate g+3 (== g-1)
#define DPP_ROR8  0x128   // src gate g+2
#define DPP_ROR12 0x12C   // src gate g+1

template<int CTRL>
__device__ __forceinline__ float dppf(float v) {
    int r = __builtin_amdgcn_update_dpp(0, __builtin_bit_cast(int, v),
                                        CTRL, 0xF, 0xF, true);
    return __builtin_bit_cast(float, r);
}

// Force a value to stay materialized in a VGPR (defeats rematerialization /
// LDS re-load under the compiler's occupancy-minimizing regalloc).
#define PINV(x) asm volatile("" : "+v"(x))

// 4-wave producer/consumer split (r3 topology + register-residency pins):
//   waves 0,1 : recurrent scan, one state set each (4 batch elems). Per chunk:
//               bulk-load 8 precomputed accx scalars into PINNED registers
//               (one waitcnt, off-chain), then 8 steps of PURE VALU chain +
//               one ds_write (h) each. No per-step LDS reads on the chain.
//   waves 2,3 : per set: x staging, x-dot+bias (accx) precompute one chunk
//               AHEAD -> LDS, and h (one chunk BEHIND) -> projection +
//               log_softmax -> global store.
// r3 lesson (VGPR_Count=32): without pins the compiler re-reads accx from LDS
// per step and rematerializes the 11 lane-varying poly coefficients per step
// (SGPR const + v_cndmask), putting lgkm waits + ~22 extra insts on the chain.
// All FP values/order byte-identical to the verified r3 kernel.
__global__ __launch_bounds__(256, 1) void qlstm_fused(
    const float* __restrict__ x,        // (T,B,8)
    const float* __restrict__ w_gates,  // (4,4,12)
    const float* __restrict__ b_gates,  // (4,4)
    const float* __restrict__ rx_theta, // (4,4)
    const float* __restrict__ w_tag,    // (16,4)
    const float* __restrict__ b_tag,    // (16,)
    float* __restrict__ out)            // (T,B,16)
{
    __shared__ float  accL[2][2][CH][64];   // [set][buf][step][lane] accx+bias
    __shared__ float  hrng[2][2][CH][64];   // [set][buf][step][lane] h ring
    __shared__ float4 xstg[2][2][64];       // [set][buf][lane] x staging

    const int tid = threadIdx.x;
    const int wv  = tid >> 6;          // 0,1 = producers; 2,3 = consumers
    const int l   = tid & 63;
    const int e   = l >> 4;
    const int g   = (l >> 2) & 3;
    const int k   = l & 3;

    const float IV  = 0.15915494309189535f;   // 1/(2pi): v_cos takes revolutions
    const float L2E = 1.44269504088896f;
    const float LN2 = 0.69314718056f;

    if (wv < 2) {
        // ============================ producer ============================
        const int s = wv;                       // state set

        const float* wrow = w_gates + (g * 4 + k) * 12;
        float wh0 = wrow[8 + (k ^ 0)] * IV;
        float wh1 = wrow[8 + (k ^ 1)] * IV;
        float wh2 = wrow[8 + (k ^ 2)] * IV;
        float wh3 = wrow[8 + (k ^ 3)] * IV;

        // Branchless gate activation: odd deg-7 poly act = ab + q*P(q^2).
        // g==2 -> tanh (refit, err<=2e-4); else sigmoid (Taylor, err~2e-5).
        // These are LANE-VARYING (g-dependent) -> must be VGPR-resident.
        const bool gt = (g == 2);
        float ab = gt ? 0.0f : 0.5f;
        float d0 = gt ? 0.999904f  : 0.25f;
        float d1 = gt ? -0.331065f : -0.0208333333f;
        float d2 = gt ? 0.120472f  : 0.00208333333f;
        float d3 = gt ? -0.027717f : -2.10813e-4f;

        // tanh(c) deg-11 odd poly, |c| <= 2.0703 (bounded by construction).
        float u0 = 0.999160f,  u1 = -0.325289f, u2 = 0.112257f;
        float u3 = -0.028766f, u4 = 0.0043665f, u5 = -0.00028186f;

        const bool k0 = (k == 0), k1 = (k == 1), k3 = (k == 3);
        const bool g0 = (g == 0), g2 = (g == 2), glo = (g < 2);

        // Pin all loop-invariant lane-varying constants into VGPRs ONCE.
        PINV(wh0); PINV(wh1); PINV(wh2); PINV(wh3);
        PINV(ab);  PINV(d0);  PINV(d1);  PINV(d2);  PINV(d3);
        PINV(u0);  PINV(u1);  PINV(u2);  PINV(u3);  PINV(u4);  PINV(u5);

        float h = 0.f, h1 = 0.f, h2 = 0.f, h3 = 0.f, c = 0.f;

        __syncthreads();               // P0: wait for accx(chunk 0)

        for (int cc = 0; cc < NCH; ++cc) {
            const int cur = cc & 1;

            // bulk-load this chunk's 8 accx scalars (one waitcnt, off-chain),
            // then PIN them so they cannot be re-read from LDS per step.
            const float* ap = &accL[s][cur][0][l];
            float a0 = ap[0 * 64], a1 = ap[1 * 64];
            float a2 = ap[2 * 64], a3 = ap[3 * 64];
            float a4 = ap[4 * 64], a5 = ap[5 * 64];
            float a6 = ap[6 * 64], a7 = ap[7 * 64];
            asm volatile("" : "+v"(a0), "+v"(a1), "+v"(a2), "+v"(a3),
                             "+v"(a4), "+v"(a5), "+v"(a6), "+v"(a7));
            float a[CH] = { a0, a1, a2, a3, a4, a5, a6, a7 };

            float* hp = &hrng[s][cur][0][l];

            #pragma unroll
            for (int i = 0; i < CH; ++i) {
                // on-chain: h-dot as sequential fma string (h3 enters last)
                float ang = fmaf(h,  wh0, a[i]);
                ang = fmaf(h1, wh1, ang);
                ang = fmaf(h2, wh2, ang);
                ang = fmaf(h3, wh3, ang);

                const float C = __builtin_amdgcn_cosf(ang);   // cos(2*pi*ang)
                // wire-product via 3 parallel DPPs, flattened selects:
                // k0: m1*(m2*m3), k1: C*m1, k2: C*(m2*m3), k3: (C*m1)*(m2*m3)
                const float m1 = dppf<DPP_XOR1>(C);
                const float m2 = dppf<DPP_XOR2>(C);
                const float m3 = dppf<DPP_XOR3>(C);
                const float Bp  = m2 * m3;
                const float pp  = C * m1;
                const float F1  = k0 ? m1 : C;
                const float F1b = k3 ? pp : F1;
                const float F2  = k1 ? m1 : Bp;
                const float q   = F1b * F2;                   // q in [-1,1]

                // gate activation: odd deg-7 poly (valid on ALL lanes)
                const float y  = q * q;
                const float y2 = y * y;
                const float tA = fmaf(y, d1, d0);
                const float tB = fmaf(y, d3, d2);
                const float P  = fmaf(y2, tB, tA);
                const float act = fmaf(q, P, ab);

                // rotations: every lane sees all 4 gate activations
                const float rA = dppf<DPP_ROR12>(act);  // gate g+1
                const float rB = dppf<DPP_ROR8>(act);   // gate g+2
                const float rC = dppf<DPP_ROR4>(act);   // gate g+3
                // per-lane role selection -> TRUE (f,i,g~,o) on every bank.
                // bank0 picks (act,rA,rB,rC) exactly as the verified r1 code.
                const float f_ = glo ? (g0 ? act : rC) : (g2 ? rB : rA);
                const float i_ = glo ? (g0 ? rA : act) : (g2 ? rC : rB);
                const float gg = glo ? (g0 ? rB : rA) : (g2 ? act : rC);
                const float o_ = glo ? (g0 ? rC : rB) : (g2 ? rA : act);

                c = fmaf(f_, c, i_ * gg);

                // tanh(c) deg-11 odd poly (Estrin); h = (o*c)*P(c^2)
                const float cy  = c * c;
                const float cy2 = cy * cy;
                const float t1  = fmaf(cy, u1, u0);
                const float t2  = fmaf(cy, u3, u2);
                const float t3  = fmaf(cy, u5, u4);
                const float t4  = fmaf(cy2, t3, t2);
                const float Pc  = fmaf(cy2, t4, t1);
                const float voc = o_ * c;
                const float hr  = Pc * voc;

                // hand off h (true on all lanes now; consumer reads bank 0)
                hp[i * 64] = hr;

                // next-step h state: direct (no redistribute needed)
                h  = hr;
                h1 = dppf<DPP_XOR1>(hr);
                h2 = dppf<DPP_XOR2>(hr);
                h3 = dppf<DPP_XOR3>(hr);
            }
            __syncthreads();           // publish h(cc); accx(cc+1) now ready
        }
    } else {
        // ============================ consumers ============================
        const int s  = wv - 2;                  // which state set we serve
        const int b0 = blockIdx.x * 8 + s * 4;

        const float* wrow = w_gates + (g * 4 + k) * 12;
        // packed x-weights (pairs match ds_read_b128 register adjacency)
        const v2f wp0 = { wrow[0] * IV, wrow[1] * IV };
        const v2f wp1 = { wrow[2] * IV, wrow[3] * IV };
        const v2f wp2 = { wrow[4] * IV, wrow[5] * IV };
        const v2f wp3 = { wrow[6] * IV, wrow[7] * IV };
        const v2f bp  = { (b_gates[g * 4 + k] + rx_theta[g * 4 + k]) * IV, 0.0f };

        // tag weights pre-scaled by log2(e): softmax runs in base 2
        const int tag = g * 4 + k;              // lane owns one output tag
        const float wt0 = w_tag[tag * 4 + (k ^ 0)] * L2E;
        const float wt1 = w_tag[tag * 4 + (k ^ 1)] * L2E;
        const float wt2 = w_tag[tag * 4 + (k ^ 2)] * L2E;
        const float wt3 = w_tag[tag * 4 + (k ^ 3)] * L2E;
        const float bt  = b_tag[tag] * L2E;

        const int hsl = e * 16 + k;             // g==0 slot of our (e,k)
        float* outp = out + (size_t)b0 * NTAG + l;   // 64 lanes = 256B per t

        // x staging: lane covers step (l>>3) of each chunk, 16B slot (l&7).
        const float* xlane = x + (size_t)(l >> 3) * (BB * 8)
                               + (size_t)b0 * 8 + (l & 7) * 4;
        const size_t CHOFF = (size_t)CH * BB * 8;

        // ---- prologue: x(0),x(1) -> LDS; accx(0) -> accL[s][0] ----
        float4 reg = *(const float4*)(xlane);
        xstg[s][0][l] = reg;
        reg = *(const float4*)(xlane + CHOFF);
        xstg[s][1][l] = reg;
        {
            float* ap = &accL[s][0][0][l];
            #pragma unroll
            for (int i = 0; i < CH; ++i) {
                const float4 xA = xstg[s][0][i * 8 + 2 * e];
                const float4 xB = xstg[s][0][i * 8 + 2 * e + 1];
                const v2f a01 = { xA.x, xA.y }, a23 = { xA.z, xA.w };
                const v2f a45 = { xB.x, xB.y }, a67 = { xB.z, xB.w };
                v2f acc = __builtin_elementwise_fma(a01, wp0, bp);
                acc = __builtin_elementwise_fma(a23, wp1, acc);
                acc = __builtin_elementwise_fma(a45, wp2, acc);
                acc = __builtin_elementwise_fma(a67, wp3, acc);
                ap[i * 64] = acc.x + acc.y;
            }
        }
        reg = *(const float4*)(xlane + 2 * CHOFF);   // x(2), latency hidden
        __syncthreads();               // P0

        for (int cc = 0; cc < NCH; ++cc) {
            const int cur = cc & 1;

            // stage x(cc+2) into its parity buffer (x(m) lives in buf m&1)
            if (cc + 2 < NCH) {
                xstg[s][cur][l] = reg;
                const int cn = (cc + 3 < NCH) ? cc + 3 : NCH - 1;
                reg = *(const float4*)(xlane + (size_t)cn * CHOFF);
            }

            // compute accx(cc+1) -> accL[s][cur^1] (producer reads next chunk)
            if (cc + 1 < NCH) {
                float* ap = &accL[s][cur ^ 1][0][l];
                #pragma unroll
                for (int i = 0; i < CH; ++i) {
                    const float4 xA = xstg[s][cur ^ 1][i * 8 + 2 * e];
                    const float4 xB = xstg[s][cur ^ 1][i * 8 + 2 * e + 1];
                    const v2f a01 = { xA.x, xA.y }, a23 = { xA.z, xA.w };
                    const v2f a45 = { xB.x, xB.y }, a67 = { xB.z, xB.w };
                    v2f acc = __builtin_elementwise_fma(a01, wp0, bp);
                    acc = __builtin_elementwise_fma(a23, wp1, acc);
                    acc = __builtin_elementwise_fma(a45, wp2, acc);
                    acc = __builtin_elementwise_fma(a67, wp3, acc);
                    ap[i * 64] = acc.x + acc.y;
                }
            }

            // consume h(cc-1): projection + log_softmax + store
            if (cc > 0) {
                const float* hp = &hrng[s][cur ^ 1][0][hsl];
                #pragma unroll
                for (int i = 0; i < CH; ++i) {
                    // broadcast read (4 g-lanes share one address)
                    const float hv = hp[i * 64];
                    const float q1 = dppf<DPP_XOR1>(hv);
                    const float q2 = dppf<DPP_XOR2>(hv);
                    const float q3 = dppf<DPP_XOR3>(hv);

                    const float lgq = fmaf(hv, wt0, fmaf(q1, wt1, fmaf(q2, wt2,
                                         fmaf(q3, wt3, bt))));
                    const float ex = __builtin_amdgcn_exp2f(lgq);
                    float sm = ex + dppf<DPP_XOR1>(ex);
                    sm = sm + dppf<DPP_XOR2>(sm);
                    sm = sm + dppf<DPP_ROR4>(sm);
                    sm = sm + dppf<DPP_ROR8>(sm);
                    const float l2s = __builtin_amdgcn_logf(sm);   // log2(s)

                    *outp = (lgq - l2s) * LN2;
                    outp += BBN;
                }
            }
            __syncthreads();
        }

        // epilogue: drain h(63) (buffer 63&1 == 1)
        {
            const float* hp = &hrng[s][1][0][hsl];
            #pragma unroll
            for (int i = 0; i < CH; ++i) {
                const float hv = hp[i * 64];
                const float q1 = dppf<DPP_XOR1>(hv);
                const float q2 = dppf<DPP_XOR2>(hv);
                const float q3 = dppf<DPP_XOR3>(hv);

                const float lgq = fmaf(hv, wt0, fmaf(q1, wt1, fmaf(q2, wt2,
                                     fmaf(q3, wt3, bt))));
                const float ex = __builtin_amdgcn_exp2f(lgq);
                float sm = ex + dppf<DPP_XOR1>(ex);
                sm = sm + dppf<DPP_XOR2>(sm);
                sm = sm + dppf<DPP_ROR4>(sm);
                sm = sm + dppf<DPP_ROR8>(sm);
                const float l2s = __builtin_amdgcn_logf(sm);

                *outp = (lgq - l2s) * LN2;
                outp += BBN;
            }
        }
    }
}

extern "C" void kernel_launch(void* const* d_in, const int* in_sizes, int n_in,
                              void* d_out, int out_size, void* d_ws, size_t ws_size,
                              hipStream_t stream) {
    const float* x        = (const float*)d_in[0];
    const float* w_gates  = (const float*)d_in[1];
    const float* b_gates  = (const float*)d_in[2];
    const float* rx_theta = (const float*)d_in[3];
    const float* w_tag    = (const float*)d_in[4];
    const float* b_tag    = (const float*)d_in[5];
    float* out = (float*)d_out;

    qlstm_fused<<<BB / 8, 256, 0, stream>>>(x, w_gates, b_gates, rx_theta,
                                            w_tag, b_tag, out);
}

// Round 5
// 137.643 us; speedup vs baseline: 1.0636x; 1.0636x over previous
//
#include <hip/hip_runtime.h>

// Problem constants (fixed by reference).
#define TT   512
#define BB   2048
#define NTAG 16
#define CH   8              // timesteps staged per chunk
#define NCH  (TT / CH)      // 64 chunks
#define BBN  (BB * NTAG)

typedef float v2f __attribute__((ext_vector_type(2)));

// ---------- DPP helpers ----------
#define DPP_XOR1  0xB1    // quad_perm [1,0,3,2] : lane ^ 1
#define DPP_XOR2  0x4E    // quad_perm [2,3,0,1] : lane ^ 2
#define DPP_XOR3  0x1B    // quad_perm [3,2,1,0] : lane ^ 3
#define DPP_ROR4  0x124   // row_ror:4  : dst gets lane-position +3 (verified r2)
#define DPP_ROR8  0x128   // row_ror:8  : +2
#define DPP_ROR12 0x12C   // row_ror:12 : +1
#define DPP_BC0   0x00    // quad_perm [0,0,0,0] : broadcast quad lane 0
#define DPP_BC1   0x55    // quad_perm [1,1,1,1]
#define DPP_BC2   0xAA    // quad_perm [2,2,2,2]
#define DPP_BC3   0xFF    // quad_perm [3,3,3,3]

template<int CTRL>
__device__ __forceinline__ float dppf(float v) {
    int r = __builtin_amdgcn_update_dpp(0, __builtin_bit_cast(int, v),
                                        CTRL, 0xF, 0xF, true);
    return __builtin_bit_cast(float, r);
}

// Force a value to stay materialized in a VGPR.
#define PINV(x) asm volatile("" : "+v"(x))

// 4-wave producer/consumer split. r5: PRODUCER LANE LAYOUT TRANSPOSED.
//   Producer lane = e*16 + w*4 + G  (w = hidden/wire index, G = gate in QUAD).
//   Gate-role distribution is now 4 parallel quad_perm BROADCASTS (one DPP
//   level, zero cndmask) instead of ror + 2 dependent select levels; c and h
//   are true on ALL lanes. Wire-axis gathers (h-dot, cosine products) move to
//   the verified ROR4/8/12 controls with weights re-indexed by (w+j)&3.
//   Chain: 24-25 dependent levels (r4) -> 21.
//   waves 0,1 : recurrent scan (one 4-elem set each); accx bulk-loaded from
//               LDS at chunk top (pinned), 8 steps pure VALU + 1 ds_write.
//   waves 2,3 : x staging, accx precompute one chunk ahead, softmax one
//               chunk behind (consumer layout unchanged: e*16 + g*4 + k).
__global__ __launch_bounds__(256, 1) void qlstm_fused(
    const float* __restrict__ x,        // (T,B,8)
    const float* __restrict__ w_gates,  // (4,4,12)
    const float* __restrict__ b_gates,  // (4,4)
    const float* __restrict__ rx_theta, // (4,4)
    const float* __restrict__ w_tag,    // (16,4)
    const float* __restrict__ b_tag,    // (16,)
    float* __restrict__ out)            // (T,B,16)
{
    __shared__ float  accL[2][2][CH][64];   // [set][buf][step][lane] accx+bias
    __shared__ float  hrng[2][2][CH][64];   // [set][buf][step][lane] h ring
    __shared__ float4 xstg[2][2][64];       // [set][buf][lane] x staging

    const int tid = threadIdx.x;
    const int wv  = tid >> 6;          // 0,1 = producers; 2,3 = consumers
    const int l   = tid & 63;
    const int e   = l >> 4;

    const float IV  = 0.15915494309189535f;   // 1/(2pi): v_cos takes revolutions
    const float L2E = 1.44269504088896f;
    const float LN2 = 0.69314718056f;

    if (wv < 2) {
        // ============================ producer ============================
        const int s = wv;                       // state set
        const int w = (l >> 2) & 3;             // hidden/wire index (stride 4)
        const int G = l & 3;                    // gate index (in quad)

        // weight row for (gate G, hidden w)
        const float* wrow = w_gates + (G * 4 + w) * 12;
        // h-weights paired with ROR-gathered h_{w+j}
        float wh0 = wrow[8 + ((w + 0) & 3)] * IV;
        float wh1 = wrow[8 + ((w + 1) & 3)] * IV;
        float wh2 = wrow[8 + ((w + 2) & 3)] * IV;
        float wh3 = wrow[8 + ((w + 3) & 3)] * IV;

        // Branchless gate activation: odd deg-7 poly act = ab + q*P(q^2).
        // G==2 -> tanh (refit, err<=2e-4); else sigmoid (Taylor, err~2e-5).
        const bool gt = (G == 2);
        float ab = gt ? 0.0f : 0.5f;
        float d0 = gt ? 0.999904f  : 0.25f;
        float d1 = gt ? -0.331065f : -0.0208333333f;
        float d2 = gt ? 0.120472f  : 0.00208333333f;
        float d3 = gt ? -0.027717f : -2.10813e-4f;

        // tanh(c) deg-11 odd poly, |c| <= 2.0703 (bounded by construction).
        float u0 = 0.999160f,  u1 = -0.325289f, u2 = 0.112257f;
        float u3 = -0.028766f, u4 = 0.0043665f, u5 = -0.00028186f;

        const bool w0 = (w == 0), w1 = (w == 1), w3 = (w == 3);

        PINV(wh0); PINV(wh1); PINV(wh2); PINV(wh3);
        PINV(ab);  PINV(d0);  PINV(d1);  PINV(d2);  PINV(d3);
        PINV(u0);  PINV(u1);  PINV(u2);  PINV(u3);  PINV(u4);  PINV(u5);

        // accx transposed slot: consumer lane (e, g=G, k=w) = e*16 + G*4 + w
        const int atl = (l & 48) | ((l & 3) << 2) | ((l >> 2) & 3);

        float h = 0.f, hg1 = 0.f, hg2 = 0.f, hg3 = 0.f, c = 0.f;

        __syncthreads();               // P0: wait for accx(chunk 0)

        for (int cc = 0; cc < NCH; ++cc) {
            const int cur = cc & 1;

            // bulk-load this chunk's 8 accx scalars (one waitcnt, off-chain)
            const float* ap = &accL[s][cur][0][atl];
            float a0 = ap[0 * 64], a1 = ap[1 * 64];
            float a2 = ap[2 * 64], a3 = ap[3 * 64];
            float a4 = ap[4 * 64], a5 = ap[5 * 64];
            float a6 = ap[6 * 64], a7 = ap[7 * 64];
            asm volatile("" : "+v"(a0), "+v"(a1), "+v"(a2), "+v"(a3),
                             "+v"(a4), "+v"(a5), "+v"(a6), "+v"(a7));
            float a[CH] = { a0, a1, a2, a3, a4, a5, a6, a7 };

            float* hp = &hrng[s][cur][0][l];

            #pragma unroll
            for (int i = 0; i < CH; ++i) {
                // on-chain: h-dot tree (hg's are last step's parallel RORs)
                const float sA  = fmaf(h, wh0, a[i]);
                const float td1 = fmaf(hg1, wh1, sA);
                const float td2 = hg2 * wh2;
                const float td3 = fmaf(hg3, wh3, td2);
                const float ang = td1 + td3;

                const float C = __builtin_amdgcn_cosf(ang);   // cos(2*pi*ang)

                // wire products across w via ROR (n_j = C_{w+j}):
                // w0: n1*(n2*n3), w1: C*n3, w2: C*(n2*n3), w3: (C*n1)*(n2*n3)
                const float n1 = dppf<DPP_ROR12>(C);
                const float n2 = dppf<DPP_ROR8>(C);
                const float n3 = dppf<DPP_ROR4>(C);
                const float Bp = n2 * n3;
                const float pp = C * n1;
                const float F1  = w0 ? n1 : C;
                const float F1b = w3 ? pp : F1;
                const float F2  = w1 ? n3 : Bp;
                const float q   = F1b * F2;                   // q in [-1,1]

                // gate activation: odd deg-7 poly (valid on ALL lanes)
                const float y  = q * q;
                const float y2 = y * y;
                const float tA = fmaf(y, d1, d0);
                const float tB = fmaf(y, d3, d2);
                const float P  = fmaf(y2, tB, tA);
                const float act = fmaf(q, P, ab);

                // roles via quad_perm BROADCASTS (gates live in the quad):
                // one DPP level, no selects; true on every lane.
                const float F_ = dppf<DPP_BC0>(act);   // f  (gate 0)
                const float A1 = dppf<DPP_BC1>(act);   // i  (gate 1)
                const float A2 = dppf<DPP_BC2>(act);   // g~ (gate 2)
                const float O_ = dppf<DPP_BC3>(act);   // o  (gate 3)

                c = fmaf(F_, c, A1 * A2);

                // tanh(c) deg-11 odd poly (Estrin); h = (o*c)*P(c^2)
                const float cy  = c * c;
                const float cy2 = cy * cy;
                const float t1  = fmaf(cy, u1, u0);
                const float t2  = fmaf(cy, u3, u2);
                const float t3  = fmaf(cy, u5, u4);
                const float t4  = fmaf(cy2, t3, t2);
                const float Pc  = fmaf(cy2, t4, t1);
                const float voc = O_ * c;
                const float hr  = Pc * voc;

                // hand off h (true on all lanes; consumer reads w-slot, G=0)
                hp[i * 64] = hr;

                // next-step h state: own + ROR gathers of h_{w+1..3}
                h   = hr;
                hg1 = dppf<DPP_ROR12>(hr);
                hg2 = dppf<DPP_ROR8>(hr);
                hg3 = dppf<DPP_ROR4>(hr);
            }
            __syncthreads();           // publish h(cc); accx(cc+1) now ready
        }
    } else {
        // ============================ consumers ============================
        const int s  = wv - 2;                  // which state set we serve
        const int b0 = blockIdx.x * 8 + s * 4;
        const int g  = (l >> 2) & 3;
        const int k  = l & 3;

        const float* wrow = w_gates + (g * 4 + k) * 12;
        // packed x-weights (pairs match ds_read_b128 register adjacency)
        const v2f wp0 = { wrow[0] * IV, wrow[1] * IV };
        const v2f wp1 = { wrow[2] * IV, wrow[3] * IV };
        const v2f wp2 = { wrow[4] * IV, wrow[5] * IV };
        const v2f wp3 = { wrow[6] * IV, wrow[7] * IV };
        const v2f bp  = { (b_gates[g * 4 + k] + rx_theta[g * 4 + k]) * IV, 0.0f };

        // tag weights pre-scaled by log2(e): softmax runs in base 2
        const int tag = g * 4 + k;              // lane owns one output tag
        const float wt0 = w_tag[tag * 4 + (k ^ 0)] * L2E;
        const float wt1 = w_tag[tag * 4 + (k ^ 1)] * L2E;
        const float wt2 = w_tag[tag * 4 + (k ^ 2)] * L2E;
        const float wt3 = w_tag[tag * 4 + (k ^ 3)] * L2E;
        const float bt  = b_tag[tag] * L2E;

        // h slot for (elem e, hidden k) in the TRANSPOSED producer layout:
        // lane e*16 + k*4 + 0 (gate 0; h is true on all gate lanes)
        const int hsl = e * 16 + k * 4;
        float* outp = out + (size_t)b0 * NTAG + l;   // 64 lanes = 256B per t

        // x staging: lane covers step (l>>3) of each chunk, 16B slot (l&7).
        const float* xlane = x + (size_t)(l >> 3) * (BB * 8)
                               + (size_t)b0 * 8 + (l & 7) * 4;
        const size_t CHOFF = (size_t)CH * BB * 8;

        // ---- prologue: x(0),x(1) -> LDS; accx(0) -> accL[s][0] ----
        float4 reg = *(const float4*)(xlane);
        xstg[s][0][l] = reg;
        reg = *(const float4*)(xlane + CHOFF);
        xstg[s][1][l] = reg;
        {
            float* ap = &accL[s][0][0][l];
            #pragma unroll
            for (int i = 0; i < CH; ++i) {
                const float4 xA = xstg[s][0][i * 8 + 2 * e];
                const float4 xB = xstg[s][0][i * 8 + 2 * e + 1];
                const v2f a01 = { xA.x, xA.y }, a23 = { xA.z, xA.w };
                const v2f a45 = { xB.x, xB.y }, a67 = { xB.z, xB.w };
                v2f acc = __builtin_elementwise_fma(a01, wp0, bp);
                acc = __builtin_elementwise_fma(a23, wp1, acc);
                acc = __builtin_elementwise_fma(a45, wp2, acc);
                acc = __builtin_elementwise_fma(a67, wp3, acc);
                ap[i * 64] = acc.x + acc.y;
            }
        }
        reg = *(const float4*)(xlane + 2 * CHOFF);   // x(2), latency hidden
        __syncthreads();               // P0

        for (int cc = 0; cc < NCH; ++cc) {
            const int cur = cc & 1;

            // stage x(cc+2) into its parity buffer (x(m) lives in buf m&1)
            if (cc + 2 < NCH) {
                xstg[s][cur][l] = reg;
                const int cn = (cc + 3 < NCH) ? cc + 3 : NCH - 1;
                reg = *(const float4*)(xlane + (size_t)cn * CHOFF);
            }

            // compute accx(cc+1) -> accL[s][cur^1] (producer reads next chunk)
            if (cc + 1 < NCH) {
                float* ap = &accL[s][cur ^ 1][0][l];
                #pragma unroll
                for (int i = 0; i < CH; ++i) {
                    const float4 xA = xstg[s][cur ^ 1][i * 8 + 2 * e];
                    const float4 xB = xstg[s][cur ^ 1][i * 8 + 2 * e + 1];
                    const v2f a01 = { xA.x, xA.y }, a23 = { xA.z, xA.w };
                    const v2f a45 = { xB.x, xB.y }, a67 = { xB.z, xB.w };
                    v2f acc = __builtin_elementwise_fma(a01, wp0, bp);
                    acc = __builtin_elementwise_fma(a23, wp1, acc);
                    acc = __builtin_elementwise_fma(a45, wp2, acc);
                    acc = __builtin_elementwise_fma(a67, wp3, acc);
                    ap[i * 64] = acc.x + acc.y;
                }
            }

            // consume h(cc-1): projection + log_softmax + store
            if (cc > 0) {
                const float* hp = &hrng[s][cur ^ 1][0][hsl];
                #pragma unroll
                for (int i = 0; i < CH; ++i) {
                    // broadcast read (4 g-lanes share one address)
                    const float hv = hp[i * 64];
                    const float q1 = dppf<DPP_XOR1>(hv);
                    const float q2 = dppf<DPP_XOR2>(hv);
                    const float q3 = dppf<DPP_XOR3>(hv);

                    const float lgq = fmaf(hv, wt0, fmaf(q1, wt1, fmaf(q2, wt2,
                                         fmaf(q3, wt3, bt))));
                    const float ex = __builtin_amdgcn_exp2f(lgq);
                    float sm = ex + dppf<DPP_XOR1>(ex);
                    sm = sm + dppf<DPP_XOR2>(sm);
                    sm = sm + dppf<DPP_ROR4>(sm);
                    sm = sm + dppf<DPP_ROR8>(sm);
                    const float l2s = __builtin_amdgcn_logf(sm);   // log2(s)

                    *outp = (lgq - l2s) * LN2;
                    outp += BBN;
                }
            }
            __syncthreads();
        }

        // epilogue: drain h(63) (buffer 63&1 == 1)
        {
            const float* hp = &hrng[s][1][0][hsl];
            #pragma unroll
            for (int i = 0; i < CH; ++i) {
                const float hv = hp[i * 64];
                const float q1 = dppf<DPP_XOR1>(hv);
                const float q2 = dppf<DPP_XOR2>(hv);
                const float q3 = dppf<DPP_XOR3>(hv);

                const float lgq = fmaf(hv, wt0, fmaf(q1, wt1, fmaf(q2, wt2,
                                     fmaf(q3, wt3, bt))));
                const float ex = __builtin_amdgcn_exp2f(lgq);
                float sm = ex + dppf<DPP_XOR1>(ex);
                sm = sm + dppf<DPP_XOR2>(sm);
                sm = sm + dppf<DPP_ROR4>(sm);
                sm = sm + dppf<DPP_ROR8>(sm);
                const float l2s = __builtin_amdgcn_logf(sm);

                *outp = (lgq - l2s) * LN2;
                outp += BBN;
            }
        }
    }
}

extern "C" void kernel_launch(void* const* d_in, const int* in_sizes, int n_in,
                              void* d_out, int out_size, void* d_ws, size_t ws_size,
                              hipStream_t stream) {
    const float* x        = (const float*)d_in[0];
    const float* w_gates  = (const float*)d_in[1];
    const float* b_gates  = (const float*)d_in[2];
    const float* rx_theta = (const float*)d_in[3];
    const float* w_tag    = (const float*)d_in[4];
    const float* b_tag    = (const float*)d_in[5];
    float* out = (float*)d_out;

    qlstm_fused<<<BB / 8, 256, 0, stream>>>(x, w_gates, b_gates, rx_theta,
                                            w_tag, b_tag, out);
}

// Round 7
// 136.673 us; speedup vs baseline: 1.0711x; 1.0071x over previous
//
#include <hip/hip_runtime.h>

// Problem constants (fixed by reference).
#define TT   512
#define BB   2048
#define NTAG 16
#define CH   8              // timesteps staged per chunk
#define NCH  (TT / CH)      // 64 chunks
#define BBN  (BB * NTAG)

typedef float v2f __attribute__((ext_vector_type(2)));

// ---------- DPP helpers ----------
#define DPP_XOR1  0xB1    // quad_perm [1,0,3,2] : lane ^ 1
#define DPP_XOR2  0x4E    // quad_perm [2,3,0,1] : lane ^ 2
#define DPP_XOR3  0x1B    // quad_perm [3,2,1,0] : lane ^ 3
#define DPP_ROR4  0x124   // row_ror:4  : dst gets lane-position +3 (verified r2)
#define DPP_ROR8  0x128   // row_ror:8  : +2
#define DPP_ROR12 0x12C   // row_ror:12 : +1
#define DPP_BC0   0x00    // quad_perm [0,0,0,0] : broadcast quad lane 0
#define DPP_BC1   0x55    // quad_perm [1,1,1,1]
#define DPP_BC2   0xAA    // quad_perm [2,2,2,2]
#define DPP_BC3   0xFF    // quad_perm [3,3,3,3]

template<int CTRL>
__device__ __forceinline__ float dppf(float v) {
    int r = __builtin_amdgcn_update_dpp(0, __builtin_bit_cast(int, v),
                                        CTRL, 0xF, 0xF, true);
    return __builtin_bit_cast(float, r);
}

// Force a value to stay materialized in a VGPR.
#define PINV(x) asm volatile("" : "+v"(x))

// 4-wave producer/consumer split, transposed producer layout (r5) +
// skewed accx pipeline (r6) with the r6 BUG FIXED:
//   r6 failed (absmax 0.25) because DPPs were placed INSIDE ternary arms
//   (`bw ? dpp(C) : 1.0f`). If the compiler if-converts to an exec-masked
//   branch, exec-disabled SOURCE lanes read 0 under bound_ctrl=1 -> some
//   lanes' wire product collapses to 0. RULE: every update_dpp must be an
//   unconditional full-exec statement; selects operate on its RESULT only.
//   (r5's n1/n2/n3 + F1/F1b/F2 select structure restored verbatim.)
//   accx skew kept: consumers compute accx(cc+2) during chunk cc (4-deep
//   accL ring). Producer ISSUES next-chunk accx ds_reads at chunk TOP and
//   first uses them at chunk BOTTOM -> the ~120cy LDS read latency
//   (previously exposed at every chunk top, right after the publishing
//   barrier) hides under the 8-step chain. No PINV on in-flight loads.
//   tanh epilogue regroup kept (-1 level): hr = fma(voc*cy2, t4, voc*t1).
__global__ __launch_bounds__(256, 1) void qlstm_fused(
    const float* __restrict__ x,        // (T,B,8)
    const float* __restrict__ w_gates,  // (4,4,12)
    const float* __restrict__ b_gates,  // (4,4)
    const float* __restrict__ rx_theta, // (4,4)
    const float* __restrict__ w_tag,    // (16,4)
    const float* __restrict__ b_tag,    // (16,)
    float* __restrict__ out)            // (T,B,16)
{
    __shared__ float  accL[2][4][CH][64];   // [set][ring][step][lane] accx+bias
    __shared__ float  hrng[2][2][CH][64];   // [set][buf][step][lane] h ring
    __shared__ float4 xstg[2][2][64];       // [set][buf][lane] x staging

    const int tid = threadIdx.x;
    const int wv  = tid >> 6;          // 0,1 = producers; 2,3 = consumers
    const int l   = tid & 63;
    const int e   = l >> 4;

    const float IV  = 0.15915494309189535f;   // 1/(2pi): v_cos takes revolutions
    const float L2E = 1.44269504088896f;
    const float LN2 = 0.69314718056f;

    if (wv < 2) {
        // ============================ producer ============================
        const int s = wv;                       // state set
        const int w = (l >> 2) & 3;             // hidden/wire index (stride 4)
        const int G = l & 3;                    // gate index (in quad)

        // weight row for (gate G, hidden w); h-weights paired with ROR h_{w+j}
        const float* wrow = w_gates + (G * 4 + w) * 12;
        float wh0 = wrow[8 + ((w + 0) & 3)] * IV;
        float wh1 = wrow[8 + ((w + 1) & 3)] * IV;
        float wh2 = wrow[8 + ((w + 2) & 3)] * IV;
        float wh3 = wrow[8 + ((w + 3) & 3)] * IV;

        // Branchless gate activation: odd deg-7 poly act = ab + q*P(q^2).
        // G==2 -> tanh (refit, err<=2e-4); else sigmoid (Taylor, err~2e-5).
        const bool gt = (G == 2);
        float ab = gt ? 0.0f : 0.5f;
        float d0 = gt ? 0.999904f  : 0.25f;
        float d1 = gt ? -0.331065f : -0.0208333333f;
        float d2 = gt ? 0.120472f  : 0.00208333333f;
        float d3 = gt ? -0.027717f : -2.10813e-4f;

        // tanh(c) deg-11 odd poly, |c| <= 2.0703 (bounded by construction).
        float u0 = 0.999160f,  u1 = -0.325289f, u2 = 0.112257f;
        float u3 = -0.028766f, u4 = 0.0043665f, u5 = -0.00028186f;

        const bool w0 = (w == 0), w1 = (w == 1), w3 = (w == 3);

        PINV(wh0); PINV(wh1); PINV(wh2); PINV(wh3);
        PINV(ab);  PINV(d0);  PINV(d1);  PINV(d2);  PINV(d3);
        PINV(u0);  PINV(u1);  PINV(u2);  PINV(u3);  PINV(u4);  PINV(u5);

        // accx transposed slot: consumer lane (e, g=G, k=w) = e*16 + G*4 + w
        const int atl = (l & 48) | ((l & 3) << 2) | ((l >> 2) & 3);

        float h = 0.f, c = 0.f;

        __syncthreads();               // P0: accx(0), accx(1) published

        // chunk 0's accx -> regs (latency exposed once, in prologue only)
        float a[CH];
        {
            const float* ap0 = &accL[s][0][0][atl];
            #pragma unroll
            for (int i = 0; i < CH; ++i) a[i] = ap0[i * 64];
        }

        for (int cc = 0; cc < NCH; ++cc) {
            // ISSUE next chunk's accx reads now (published at the barrier
            // that started this chunk); first use is after the step loop ->
            // the pre-barrier lgkm drain is the wait point (fully hidden).
            const float* np = &accL[s][(cc + 1) & 3][0][atl];
            float n[CH];
            #pragma unroll
            for (int i = 0; i < CH; ++i) n[i] = np[i * 64];

            float* hp = &hrng[s][cc & 1][0][l];

            #pragma unroll
            for (int i = 0; i < CH; ++i) {
                // on-chain: h-dot (unconditional single-use DPP operands)
                const float s1 = fmaf(h, wh0, a[i]);
                const float s2 = fmaf(dppf<DPP_ROR12>(h), wh1, s1);
                const float mm = dppf<DPP_ROR8>(h) * wh2;
                const float s3 = fmaf(dppf<DPP_ROR4>(h), wh3, mm);
                const float ang = s2 + s3;

                const float C = __builtin_amdgcn_cosf(ang);   // cos(2*pi*ang)

                // wire products across w (n_j = C_{w+j}) — r5 structure:
                // ALL DPPs unconditional full-exec; selects on results only.
                // w0: n1*(n2*n3), w1: C*n3, w2: C*(n2*n3), w3: (C*n1)*(n2*n3)
                const float n1 = dppf<DPP_ROR12>(C);
                const float n2 = dppf<DPP_ROR8>(C);
                const float n3 = dppf<DPP_ROR4>(C);
                const float Bp = n2 * n3;
                const float pp = C * n1;
                const float F1  = w0 ? n1 : C;
                const float F1b = w3 ? pp : F1;
                const float F2  = w1 ? n3 : Bp;
                const float q   = F1b * F2;                   // q in [-1,1]

                // gate activation: odd deg-7 poly (valid on ALL lanes)
                const float y  = q * q;
                const float y2 = y * y;
                const float tA = fmaf(y, d1, d0);
                const float tB = fmaf(y, d3, d2);
                const float P  = fmaf(y2, tB, tA);
                const float act = fmaf(q, P, ab);

                // roles via quad_perm broadcasts (gates live in the quad)
                const float A2  = dppf<DPP_BC2>(act);
                const float A12 = dppf<DPP_BC1>(act) * A2;
                c = fmaf(dppf<DPP_BC0>(act), c, A12);

                // tanh(c) deg-11 odd poly, distributed form (-1 level):
                // hr = voc*(t1 + cy2*t4) = fma(voc*cy2, t4, voc*t1)
                const float voc = dppf<DPP_BC3>(act) * c;
                const float cy  = c * c;
                const float cy2 = cy * cy;
                const float t1  = fmaf(cy, u1, u0);
                const float t2  = fmaf(cy, u3, u2);
                const float t3  = fmaf(cy, u5, u4);
                const float t4  = fmaf(cy2, t3, t2);
                const float m1v = voc * t1;
                const float vc2 = voc * cy2;
                const float hr  = fmaf(vc2, t4, m1v);

                // hand off h (true on all lanes; consumer reads w-slot)
                hp[i * 64] = hr;
                h = hr;
            }

            #pragma unroll
            for (int i = 0; i < CH; ++i) a[i] = n[i];

            __syncthreads();           // publish h(cc); accx(cc+2) now ready
        }
    } else {
        // ============================ consumers ============================
        const int s  = wv - 2;                  // which state set we serve
        const int b0 = blockIdx.x * 8 + s * 4;
        const int g  = (l >> 2) & 3;
        const int k  = l & 3;

        const float* wrow = w_gates + (g * 4 + k) * 12;
        // packed x-weights (pairs match ds_read_b128 register adjacency)
        const v2f wp0 = { wrow[0] * IV, wrow[1] * IV };
        const v2f wp1 = { wrow[2] * IV, wrow[3] * IV };
        const v2f wp2 = { wrow[4] * IV, wrow[5] * IV };
        const v2f wp3 = { wrow[6] * IV, wrow[7] * IV };
        const v2f bp  = { (b_gates[g * 4 + k] + rx_theta[g * 4 + k]) * IV, 0.0f };

        // tag weights pre-scaled by log2(e): softmax runs in base 2
        const int tag = g * 4 + k;              // lane owns one output tag
        const float wt0 = w_tag[tag * 4 + (k ^ 0)] * L2E;
        const float wt1 = w_tag[tag * 4 + (k ^ 1)] * L2E;
        const float wt2 = w_tag[tag * 4 + (k ^ 2)] * L2E;
        const float wt3 = w_tag[tag * 4 + (k ^ 3)] * L2E;
        const float bt  = b_tag[tag] * L2E;

        // h slot for (elem e, hidden k) in the transposed producer layout
        const int hsl = e * 16 + k * 4;
        float* outp = out + (size_t)b0 * NTAG + l;   // 64 lanes = 256B per t

        // x staging: lane covers step (l>>3) of each chunk, 16B slot (l&7).
        const float* xlane = x + (size_t)(l >> 3) * (BB * 8)
                               + (size_t)b0 * 8 + (l & 7) * 4;
        const size_t CHOFF = (size_t)CH * BB * 8;

        // accx(m) from x(m) staged in xstg buf (m&1) -> accL ring (m&3)
        auto compute_acc = [&](int xbuf, int ring) {
            float* ap = &accL[s][ring][0][l];
            #pragma unroll
            for (int i = 0; i < CH; ++i) {
                const float4 xA = xstg[s][xbuf][i * 8 + 2 * e];
                const float4 xB = xstg[s][xbuf][i * 8 + 2 * e + 1];
                const v2f a01 = { xA.x, xA.y }, a23 = { xA.z, xA.w };
                const v2f a45 = { xB.x, xB.y }, a67 = { xB.z, xB.w };
                v2f acc = __builtin_elementwise_fma(a01, wp0, bp);
                acc = __builtin_elementwise_fma(a23, wp1, acc);
                acc = __builtin_elementwise_fma(a45, wp2, acc);
                acc = __builtin_elementwise_fma(a67, wp3, acc);
                ap[i * 64] = acc.x + acc.y;
            }
        };

        // ---- prologue: x(0),x(1) -> LDS; accx(0),accx(1); x(2) -> LDS ----
        float4 reg = *(const float4*)(xlane);
        xstg[s][0][l] = reg;                         // x0 -> buf0
        reg = *(const float4*)(xlane + CHOFF);
        xstg[s][1][l] = reg;                         // x1 -> buf1
        compute_acc(0, 0);                           // accx(0)
        compute_acc(1, 1);                           // accx(1)
        reg = *(const float4*)(xlane + 2 * CHOFF);
        xstg[s][0][l] = reg;                         // x2 -> buf0 (2&1)
        reg = *(const float4*)(xlane + 3 * CHOFF);   // x(3) in flight
        __syncthreads();               // P0

        for (int cc = 0; cc < NCH; ++cc) {
            const int cur = cc & 1;

            // compute accx(cc+2) from x(cc+2) [buf (cc+2)&1 == cur]
            if (cc + 2 < NCH) compute_acc(cur, (cc + 2) & 3);

            // stage x(cc+3) into buf (cc+3)&1 == cur^1; prefetch x(cc+4)
            if (cc + 3 < NCH) {
                xstg[s][cur ^ 1][l] = reg;
                const int cn = (cc + 4 < NCH) ? cc + 4 : NCH - 1;
                reg = *(const float4*)(xlane + (size_t)cn * CHOFF);
            }

            // consume h(cc-1): projection + log_softmax + store
            if (cc > 0) {
                const float* hp = &hrng[s][cur ^ 1][0][hsl];
                #pragma unroll
                for (int i = 0; i < CH; ++i) {
                    // broadcast read (4 g-lanes share one address)
                    const float hv = hp[i * 64];
                    const float q1 = dppf<DPP_XOR1>(hv);
                    const float q2 = dppf<DPP_XOR2>(hv);
                    const float q3 = dppf<DPP_XOR3>(hv);

                    const float lgq = fmaf(hv, wt0, fmaf(q1, wt1, fmaf(q2, wt2,
                                         fmaf(q3, wt3, bt))));
                    const float ex = __builtin_amdgcn_exp2f(lgq);
                    float sm = ex + dppf<DPP_XOR1>(ex);
                    sm = sm + dppf<DPP_XOR2>(sm);
                    sm = sm + dppf<DPP_ROR4>(sm);
                    sm = sm + dppf<DPP_ROR8>(sm);
                    const float l2s = __builtin_amdgcn_logf(sm);   // log2(s)

                    *outp = (lgq - l2s) * LN2;
                    outp += BBN;
                }
            }
            __syncthreads();
        }

        // epilogue: drain h(63) (buffer 63&1 == 1)
        {
            const float* hp = &hrng[s][1][0][hsl];
            #pragma unroll
            for (int i = 0; i < CH; ++i) {
                const float hv = hp[i * 64];
                const float q1 = dppf<DPP_XOR1>(hv);
                const float q2 = dppf<DPP_XOR2>(hv);
                const float q3 = dppf<DPP_XOR3>(hv);

                const float lgq = fmaf(hv, wt0, fmaf(q1, wt1, fmaf(q2, wt2,
                                     fmaf(q3, wt3, bt))));
                const float ex = __builtin_amdgcn_exp2f(lgq);
                float sm = ex + dppf<DPP_XOR1>(ex);
                sm = sm + dppf<DPP_XOR2>(sm);
                sm = sm + dppf<DPP_ROR4>(sm);
                sm = sm + dppf<DPP_ROR8>(sm);
                const float l2s = __builtin_amdgcn_logf(sm);

                *outp = (lgq - l2s) * LN2;
                outp += BBN;
            }
        }
    }
}

extern "C" void kernel_launch(void* const* d_in, const int* in_sizes, int n_in,
                              void* d_out, int out_size, void* d_ws, size_t ws_size,
                              hipStream_t stream) {
    const float* x        = (const float*)d_in[0];
    const float* w_gates  = (const float*)d_in[1];
    const float* b_gates  = (const float*)d_in[2];
    const float* rx_theta = (const float*)d_in[3];
    const float* w_tag    = (const float*)d_in[4];
    const float* b_tag    = (const float*)d_in[5];
    float* out = (float*)d_out;

    qlstm_fused<<<BB / 8, 256, 0, stream>>>(x, w_gates, b_gates, rx_theta,
                                            w_tag, b_tag, out);
}